// Round 11
// baseline (381.907 us; speedup 1.0000x reference)
//
#include <hip/hip_runtime.h>
#include <hip/hip_bf16.h>
#include <math.h>

// ---------------------------------------------------------------------------
// RESKnorm GCN, CSR-based (no float atomics), f32 everywhere.
//   CSR: histogram + 2-dispatch scan + per-node-cursor scatter fill.
//   fill FUSED with lin0 using HALF-COLUMN W tiles (16KB LDS).
//   lin1/2/3 FUSED into agg epilogues, BARRIER-FREE: after the cross-quarter
//   shuffle reduce every lane holds its channel block of h, so the lin tail
//   broadcasts h via in-quarter __shfl (no LDS hrow, no end __syncthreads)
//   -> waves retire independently (R10's end barrier cost max-of-4-degrees
//   inflation on the gather loop). Epilogue computed redundantly per quarter.
// N=50000, E=800000, NFEAT=128, NHID=64, NCLASS=40, GROUPS=32 (2 ch/group)
// ---------------------------------------------------------------------------

#define EPS 1e-5f
#define SCAN_BLK 256

// ---------------- CSR build ----------------
__global__ void count_kernel(const int* __restrict__ tgt, int* __restrict__ cnt,
                             int E) {
    int e = blockIdx.x * blockDim.x + threadIdx.x;
    if (e < E) atomicAdd(&cnt[tgt[e]], 1);
}

__global__ void scan_p1(const int* __restrict__ cnt, int* __restrict__ bsum,
                        int n) {
    __shared__ int lds[SCAN_BLK];
    int i = blockIdx.x * SCAN_BLK + threadIdx.x;
    lds[threadIdx.x] = (i < n) ? cnt[i] : 0;
    __syncthreads();
    for (int off = SCAN_BLK / 2; off; off >>= 1) {
        if (threadIdx.x < off) lds[threadIdx.x] += lds[threadIdx.x + off];
        __syncthreads();
    }
    if (threadIdx.x == 0) bsum[blockIdx.x] = lds[0];
}

// p2+p3 fused: each block recomputes its exclusive offset over bsum, then
// local inclusive scan of cnt -> rowptr/cursor.
__global__ void scan_p23(const int* __restrict__ cnt, const int* __restrict__ bsum,
                         int* __restrict__ rowptr, int* __restrict__ cursor,
                         int n) {
    __shared__ int lds[SCAN_BLK];
    __shared__ int boff_s;
    int p = 0;
    for (int i = threadIdx.x; i < (int)blockIdx.x; i += SCAN_BLK) p += bsum[i];
    lds[threadIdx.x] = p;
    __syncthreads();
    for (int off = SCAN_BLK / 2; off; off >>= 1) {
        if (threadIdx.x < off) lds[threadIdx.x] += lds[threadIdx.x + off];
        __syncthreads();
    }
    if (threadIdx.x == 0) boff_s = lds[0];
    __syncthreads();
    int boff = boff_s;
    __syncthreads();
    int i = blockIdx.x * SCAN_BLK + threadIdx.x;
    int v = (i < n) ? cnt[i] : 0;
    lds[threadIdx.x] = v;
    __syncthreads();
    for (int off = 1; off < SCAN_BLK; off <<= 1) {
        int t = (threadIdx.x >= off) ? lds[threadIdx.x - off] : 0;
        __syncthreads();
        lds[threadIdx.x] += t;
        __syncthreads();
    }
    int excl = boff + lds[threadIdx.x] - v;
    if (i < n) {
        rowptr[i] = excl;
        cursor[i] = excl;
        if (i == n - 1) rowptr[n] = excl + v;
    }
}

// ---------------- fused fill + lin0 (half-column 16KB W tiles) -------------
__global__ void fill_lin0_kernel(const int* __restrict__ src,
                                 const int* __restrict__ tgt,
                                 const float* __restrict__ mv,
                                 int* __restrict__ cursor,
                                 long long* __restrict__ ep, int E,
                                 const float* __restrict__ X,
                                 const float4* __restrict__ W4,   // [128*16]
                                 const float4* __restrict__ B4,   // [16]
                                 float4* __restrict__ S4out, int n,
                                 int fillBlocks, int halfBlocks) {
    __shared__ float4 Wl[128 * 8];
    __shared__ float4 Bl8[8];
    if (blockIdx.x < (unsigned)fillBlocks) {
        int e = blockIdx.x * blockDim.x + threadIdx.x;
        if (e >= E) return;
        int pos = atomicAdd(&cursor[tgt[e]], 1);
        long long v = (long long)(unsigned)src[e] |
                      ((long long)__float_as_int(mv[e]) << 32);
        ep[pos] = v;
        return;
    }
    int t = blockIdx.x - fillBlocks;
    int half = (t >= halfBlocks) ? 1 : 0;
    int bi = t - half * halfBlocks;
    for (int i = threadIdx.x; i < 128 * 8; i += blockDim.x)
        Wl[i] = W4[(i >> 3) * 16 + half * 8 + (i & 7)];
    if (threadIdx.x < 8) Bl8[threadIdx.x] = B4[half * 8 + threadIdx.x];
    __syncthreads();
    int idx = bi * blockDim.x + threadIdx.x;
    if (idx >= n * 8) return;
    int row = idx >> 3;
    int c8 = idx & 7;
    const float* xr = X + (long)row * 128;
    float4 acc = Bl8[c8];
#pragma unroll 8
    for (int k = 0; k < 128; ++k) {
        float xv = xr[k];
        float4 w = Wl[k * 8 + c8];
        acc.x = fmaf(xv, w.x, acc.x);
        acc.y = fmaf(xv, w.y, acc.y);
        acc.z = fmaf(xv, w.z, acc.z);
        acc.w = fmaf(xv, w.w, acc.w);
    }
    S4out[(long)row * 16 + half * 8 + c8] = acc;
}

// ---------------- quarter-wave aggregation core ----------------
#define FMA4(A, V, W4)                                                        \
    A.x = fmaf(V.x, W4, A.x); A.y = fmaf(V.y, W4, A.y);                       \
    A.z = fmaf(V.z, W4, A.z); A.w = fmaf(V.w, W4, A.w);

#define AGG4_BODY(R4)                                                         \
    int beg = rowptr[wid], end = rowptr[wid + 1];                             \
    float4 a0 = make_float4(0.f, 0.f, 0.f, 0.f), a1 = a0, a2 = a0, a3 = a0;   \
    int j = beg;                                                              \
    for (; j + 16 <= end; j += 16) {                                          \
        long long p0 = ep[j + q], p1 = ep[j + 4 + q];                         \
        long long p2 = ep[j + 8 + q], p3 = ep[j + 12 + q];                    \
        float4 v0 = S4[(long)(int)(unsigned)p0 * R4 + sub];                   \
        float4 v1 = S4[(long)(int)(unsigned)p1 * R4 + sub];                   \
        float4 v2 = S4[(long)(int)(unsigned)p2 * R4 + sub];                   \
        float4 v3 = S4[(long)(int)(unsigned)p3 * R4 + sub];                   \
        float w0 = __int_as_float((int)(p0 >> 32));                           \
        float w1 = __int_as_float((int)(p1 >> 32));                           \
        float w2 = __int_as_float((int)(p2 >> 32));                           \
        float w3 = __int_as_float((int)(p3 >> 32));                           \
        FMA4(a0, v0, w0) FMA4(a1, v1, w1) FMA4(a2, v2, w2) FMA4(a3, v3, w3)   \
    }                                                                         \
    for (; j + 4 <= end; j += 4) {                                            \
        long long p0 = ep[j + q];                                             \
        float4 v0 = S4[(long)(int)(unsigned)p0 * R4 + sub];                   \
        float w0 = __int_as_float((int)(p0 >> 32));                           \
        FMA4(a0, v0, w0)                                                      \
    }                                                                         \
    if (j < end) {                                                            \
        int eidx = j + q;                                                     \
        long long p0 = ep[(eidx < end) ? eidx : (end - 1)];                   \
        float4 v0 = S4[(long)(int)(unsigned)p0 * R4 + sub];                   \
        float w0 = (eidx < end) ? __int_as_float((int)(p0 >> 32)) : 0.f;      \
        FMA4(a0, v0, w0)                                                      \
    }                                                                         \
    float4 acc;                                                               \
    acc.x = (a0.x + a1.x) + (a2.x + a3.x);                                    \
    acc.y = (a0.y + a1.y) + (a2.y + a3.y);                                    \
    acc.z = (a0.z + a1.z) + (a2.z + a3.z);                                    \
    acc.w = (a0.w + a1.w) + (a2.w + a3.w);                                    \
    acc.x += __shfl_xor(acc.x, 16); acc.y += __shfl_xor(acc.y, 16);           \
    acc.z += __shfl_xor(acc.z, 16); acc.w += __shfl_xor(acc.w, 16);           \
    acc.x += __shfl_xor(acc.x, 32); acc.y += __shfl_xor(acc.y, 32);           \
    acc.z += __shfl_xor(acc.z, 32); acc.w += __shfl_xor(acc.w, 32);

// barrier-free in-wave lin tail: h (per-lane channel block, identical across
// quarters) broadcast via in-quarter __shfl; quarter q covers k in [16q,16q+16)
// in ascending order (k = 16q + 4t + c) -> same summation order as before.
#define LIN_TAIL_SHFL(C4OUT)                                                  \
    float4 o = make_float4(0.f, 0.f, 0.f, 0.f);                               \
    _Pragma("unroll")                                                         \
    for (int t = 0; t < 4; ++t) {                                             \
        int jj = 4 * q + t;                                                   \
        int sl = (lane & 48) | jj;                                            \
        float4 hv;                                                            \
        hv.x = __shfl(h.x, sl); hv.y = __shfl(h.y, sl);                       \
        hv.z = __shfl(h.z, sl); hv.w = __shfl(h.w, sl);                       \
        if (sub < C4OUT) {                                                    \
            const float4* wr = &Wl[(4 * jj) * C4OUT + sub];                   \
            FMA4(o, wr[0], hv.x) FMA4(o, wr[C4OUT], hv.y)                     \
            FMA4(o, wr[2 * C4OUT], hv.z) FMA4(o, wr[3 * C4OUT], hv.w)         \
        }                                                                     \
    }                                                                         \
    o.x += __shfl_xor(o.x, 16); o.y += __shfl_xor(o.y, 16);                   \
    o.z += __shfl_xor(o.z, 16); o.w += __shfl_xor(o.w, 16);                   \
    o.x += __shfl_xor(o.x, 32); o.y += __shfl_xor(o.y, 32);                   \
    o.z += __shfl_xor(o.z, 32); o.w += __shfl_xor(o.w, 32);                   \
    if (q == 0 && sub < C4OUT) {                                              \
        float4 b = Bl[sub];                                                   \
        o.x += b.x; o.y += b.y; o.z += b.z; o.w += b.w;                       \
        S4out[(long)wid * C4OUT + sub] = o;                                   \
    }

// layer 0: h = relu(agg(S)); write H; S_next = h@W1+b1
__global__ void agg_relu_lin_kernel(const float4* __restrict__ S4,
                                    const int* __restrict__ rowptr,
                                    const long long* __restrict__ ep,
                                    const float4* __restrict__ W4,  // [64*16]
                                    const float4* __restrict__ B4,  // [16]
                                    float4* __restrict__ H4,
                                    float4* __restrict__ S4out, int n) {
    __shared__ float4 Wl[64 * 16];
    __shared__ float4 Bl[16];
    for (int i = threadIdx.x; i < 64 * 16; i += blockDim.x) Wl[i] = W4[i];
    if (threadIdx.x < 16) Bl[threadIdx.x] = B4[threadIdx.x];
    __syncthreads();   // only barrier: W-tile staging
    int wid = (blockIdx.x * blockDim.x + threadIdx.x) >> 6;
    int lane = threadIdx.x & 63;
    int q = lane >> 4, sub = lane & 15;
    if (wid >= n) return;
    AGG4_BODY(16)
    float4 h = make_float4(fmaxf(acc.x, 0.f), fmaxf(acc.y, 0.f),
                           fmaxf(acc.z, 0.f), fmaxf(acc.w, 0.f));
    if (q == 0) H4[(long)wid * 16 + sub] = h;
    LIN_TAIL_SHFL(16)
}

// layers 1-2: h = gn(relu(agg)) + H (in-place); S_next = h@W+b
template <int C4OUT>
__global__ void agg_gn_lin_kernel(const float4* __restrict__ S4,
                                  const int* __restrict__ rowptr,
                                  const long long* __restrict__ ep,
                                  const float4* __restrict__ gamma,
                                  const float4* __restrict__ beta,
                                  const float4* __restrict__ W4,  // [64*C4OUT]
                                  const float4* __restrict__ B4,  // [C4OUT]
                                  float4* __restrict__ H4,
                                  float4* __restrict__ S4out, int n) {
    __shared__ float4 Wl[64 * C4OUT];
    __shared__ float4 Bl[C4OUT];
    for (int i = threadIdx.x; i < 64 * C4OUT; i += blockDim.x) Wl[i] = W4[i];
    if (threadIdx.x < C4OUT) Bl[threadIdx.x] = B4[threadIdx.x];
    __syncthreads();   // only barrier: W-tile staging
    int wid = (blockIdx.x * blockDim.x + threadIdx.x) >> 6;
    int lane = threadIdx.x & 63;
    int q = lane >> 4, sub = lane & 15;
    if (wid >= n) return;
    AGG4_BODY(16)
    // epilogue in ALL lanes (each quarter computes identical h for its sub)
    float p0 = fmaxf(acc.x, 0.f), p1 = fmaxf(acc.y, 0.f);
    float p2 = fmaxf(acc.z, 0.f), p3 = fmaxf(acc.w, 0.f);
    float dA = 0.5f * (p0 - p1);
    float dB = 0.5f * (p2 - p3);
    float rsA = rsqrtf(dA * dA + EPS);
    float rsB = rsqrtf(dB * dB + EPS);
    float4 g = gamma[sub], be = beta[sub];
    long off = (long)wid * 16 + sub;
    float4 h = H4[off];
    h.x += dA * rsA * g.x + be.x;
    h.y += -dA * rsA * g.y + be.y;
    h.z += dB * rsB * g.z + be.z;
    h.w += -dB * rsB * g.w + be.w;
    if (q == 0) H4[off] = h;
    LIN_TAIL_SHFL(C4OUT)
}

// layer 3: log_softmax over 40 classes (10 float4 per row; sub<10 valid)
__global__ void agg_lsm_kernel(const float4* __restrict__ S4,
                               const int* __restrict__ rowptr,
                               const long long* __restrict__ ep,
                               float4* __restrict__ out4, int n) {
    int wid = (blockIdx.x * blockDim.x + threadIdx.x) >> 6;
    int lane = threadIdx.x & 63;
    int q = lane >> 4;
    int sub0 = lane & 15;
    int sub = (sub0 < 10) ? sub0 : 9;  // clamp: in-bounds dup loads, ignored
    if (wid >= n) return;
    AGG4_BODY(10)
    bool valid = sub0 < 10;
    float m = valid ? fmaxf(fmaxf(acc.x, acc.y), fmaxf(acc.z, acc.w)) : -INFINITY;
#pragma unroll
    for (int mk = 8; mk; mk >>= 1) m = fmaxf(m, __shfl_xor(m, mk));
    float ex = valid ? (expf(acc.x - m) + expf(acc.y - m) +
                        expf(acc.z - m) + expf(acc.w - m)) : 0.f;
#pragma unroll
    for (int mk = 8; mk; mk >>= 1) ex += __shfl_xor(ex, mk);
    float l = m + logf(ex);
    if (q == 0 && valid)
        out4[(long)wid * 10 + sub0] =
            make_float4(acc.x - l, acc.y - l, acc.z - l, acc.w - l);
}

extern "C" void kernel_launch(void* const* d_in, const int* in_sizes, int n_in,
                              void* d_out, int out_size, void* d_ws,
                              size_t ws_size, hipStream_t stream) {
    const float* x = (const float*)d_in[0];
    const int* src = (const int*)d_in[1];
    const int* tgt = (const int*)d_in[2];
    const float* mv = (const float*)d_in[3];
    const float* W0 = (const float*)d_in[4];
    const float* b0 = (const float*)d_in[5];
    const float* W1 = (const float*)d_in[6];
    const float* b1 = (const float*)d_in[7];
    const float* W2 = (const float*)d_in[8];
    const float* b2 = (const float*)d_in[9];
    const float* W3 = (const float*)d_in[10];
    const float* b3 = (const float*)d_in[11];
    const float* g1 = (const float*)d_in[12];
    const float* beta1 = (const float*)d_in[13];
    const float* g2 = (const float*)d_in[14];
    const float* beta2 = (const float*)d_in[15];

    const int N = in_sizes[0] / 128;
    const int E = in_sizes[1];

    float* buf_s0 = (float*)d_ws;               // [N,64] S ping
    float* buf_s1 = buf_s0 + (size_t)N * 64;    // [N,64] S pong
    float* buf_h = buf_s1 + (size_t)N * 64;     // [N,64] h / residual
    int* rowptr = (int*)(buf_h + (size_t)N * 64);  // [N+1]
    int* cursor = rowptr + (N + 1);             // [N]
    int* cnt = cursor + N;                      // [N]
    int* bsum = cnt + N;                        // [<=1024]
    long long* epack = (long long*)(((uintptr_t)(bsum + 1024) + 15) & ~(uintptr_t)15);

    const int BLK = 256;
    auto grid = [](long total, int blk) { return (int)((total + blk - 1) / blk); };
    const int scanBlocks = grid(N, SCAN_BLK);
    const int fillBlocks = grid(E, BLK);
    const int halfBlocks = grid((long)N * 8, BLK);

    // ---- CSR build ----
    hipMemsetAsync(cnt, 0, (size_t)N * sizeof(int), stream);
    count_kernel<<<grid(E, BLK), BLK, 0, stream>>>(tgt, cnt, E);
    scan_p1<<<scanBlocks, SCAN_BLK, 0, stream>>>(cnt, bsum, N);
    scan_p23<<<scanBlocks, SCAN_BLK, 0, stream>>>(cnt, bsum, rowptr, cursor, N);

    // ---- fused: CSR fill + layer-0 linear (half-tile LDS) -> S0 ----
    fill_lin0_kernel<<<fillBlocks + 2 * halfBlocks, BLK, 0, stream>>>(
        src, tgt, mv, cursor, epack, E, x, (const float4*)W0, (const float4*)b0,
        (float4*)buf_s0, N, fillBlocks, halfBlocks);

    const int aggBlocks = grid((long)N * 64, BLK);  // 4 waves (nodes) per block

    // ---- layer 0 agg + lin1: gathers S0 -> H, S1 ----
    agg_relu_lin_kernel<<<aggBlocks, BLK, 0, stream>>>(
        (const float4*)buf_s0, rowptr, epack, (const float4*)W1,
        (const float4*)b1, (float4*)buf_h, (float4*)buf_s1, N);

    // ---- layer 1 agg + lin2: gathers S1 -> H (in-place), S0 ----
    agg_gn_lin_kernel<16><<<aggBlocks, BLK, 0, stream>>>(
        (const float4*)buf_s1, rowptr, epack, (const float4*)g1,
        (const float4*)beta1, (const float4*)W2, (const float4*)b2,
        (float4*)buf_h, (float4*)buf_s0, N);

    // ---- layer 2 agg + lin3: gathers S0 -> H (in-place), S1 as [N,40] ----
    agg_gn_lin_kernel<10><<<aggBlocks, BLK, 0, stream>>>(
        (const float4*)buf_s0, rowptr, epack, (const float4*)g2,
        (const float4*)beta2, (const float4*)W3, (const float4*)b3,
        (float4*)buf_h, (float4*)buf_s1, N);

    // ---- layer 3: out = log_softmax(agg(S1)) ----
    agg_lsm_kernel<<<aggBlocks, BLK, 0, stream>>>(
        (const float4*)buf_s1, rowptr, epack, (float4*)d_out, N);
}

// Round 12
// 362.328 us; speedup vs baseline: 1.0540x; 1.0540x over previous
//
#include <hip/hip_runtime.h>
#include <hip/hip_bf16.h>
#include <math.h>

// ---------------------------------------------------------------------------
// RESKnorm GCN, CSR-based (no float atomics), f32 everywhere.
//   CSR: histogram + 2-dispatch scan + per-node-cursor scatter fill.
//   fill FUSED with lin0 using HALF-COLUMN W tiles (16KB LDS).
//   lin1/2/3 FUSED into agg epilogues via PER-WAVE LDS hrow broadcast with
//   NO end barrier: hrow[w] is wave-private, so intra-wave ds_write->ds_read
//   only needs the compiler's lgkmcnt wait (R10 had a needless __syncthreads
//   -> max-of-4-degrees inflation; R11's shuffle tail was VALU-heavier).
//   Waves retire independently; only barrier is W-tile staging.
// N=50000, E=800000, NFEAT=128, NHID=64, NCLASS=40, GROUPS=32 (2 ch/group)
// ---------------------------------------------------------------------------

#define EPS 1e-5f
#define SCAN_BLK 256

// ---------------- CSR build ----------------
__global__ void count_kernel(const int* __restrict__ tgt, int* __restrict__ cnt,
                             int E) {
    int e = blockIdx.x * blockDim.x + threadIdx.x;
    if (e < E) atomicAdd(&cnt[tgt[e]], 1);
}

__global__ void scan_p1(const int* __restrict__ cnt, int* __restrict__ bsum,
                        int n) {
    __shared__ int lds[SCAN_BLK];
    int i = blockIdx.x * SCAN_BLK + threadIdx.x;
    lds[threadIdx.x] = (i < n) ? cnt[i] : 0;
    __syncthreads();
    for (int off = SCAN_BLK / 2; off; off >>= 1) {
        if (threadIdx.x < off) lds[threadIdx.x] += lds[threadIdx.x + off];
        __syncthreads();
    }
    if (threadIdx.x == 0) bsum[blockIdx.x] = lds[0];
}

// p2+p3 fused: each block recomputes its exclusive offset over bsum, then
// local inclusive scan of cnt -> rowptr/cursor.
__global__ void scan_p23(const int* __restrict__ cnt, const int* __restrict__ bsum,
                         int* __restrict__ rowptr, int* __restrict__ cursor,
                         int n) {
    __shared__ int lds[SCAN_BLK];
    __shared__ int boff_s;
    int p = 0;
    for (int i = threadIdx.x; i < (int)blockIdx.x; i += SCAN_BLK) p += bsum[i];
    lds[threadIdx.x] = p;
    __syncthreads();
    for (int off = SCAN_BLK / 2; off; off >>= 1) {
        if (threadIdx.x < off) lds[threadIdx.x] += lds[threadIdx.x + off];
        __syncthreads();
    }
    if (threadIdx.x == 0) boff_s = lds[0];
    __syncthreads();
    int boff = boff_s;
    __syncthreads();
    int i = blockIdx.x * SCAN_BLK + threadIdx.x;
    int v = (i < n) ? cnt[i] : 0;
    lds[threadIdx.x] = v;
    __syncthreads();
    for (int off = 1; off < SCAN_BLK; off <<= 1) {
        int t = (threadIdx.x >= off) ? lds[threadIdx.x - off] : 0;
        __syncthreads();
        lds[threadIdx.x] += t;
        __syncthreads();
    }
    int excl = boff + lds[threadIdx.x] - v;
    if (i < n) {
        rowptr[i] = excl;
        cursor[i] = excl;
        if (i == n - 1) rowptr[n] = excl + v;
    }
}

// ---------------- fused fill + lin0 (half-column 16KB W tiles) -------------
__global__ void fill_lin0_kernel(const int* __restrict__ src,
                                 const int* __restrict__ tgt,
                                 const float* __restrict__ mv,
                                 int* __restrict__ cursor,
                                 long long* __restrict__ ep, int E,
                                 const float* __restrict__ X,
                                 const float4* __restrict__ W4,   // [128*16]
                                 const float4* __restrict__ B4,   // [16]
                                 float4* __restrict__ S4out, int n,
                                 int fillBlocks, int halfBlocks) {
    __shared__ float4 Wl[128 * 8];
    __shared__ float4 Bl8[8];
    if (blockIdx.x < (unsigned)fillBlocks) {
        int e = blockIdx.x * blockDim.x + threadIdx.x;
        if (e >= E) return;
        int pos = atomicAdd(&cursor[tgt[e]], 1);
        long long v = (long long)(unsigned)src[e] |
                      ((long long)__float_as_int(mv[e]) << 32);
        ep[pos] = v;
        return;
    }
    int t = blockIdx.x - fillBlocks;
    int half = (t >= halfBlocks) ? 1 : 0;
    int bi = t - half * halfBlocks;
    for (int i = threadIdx.x; i < 128 * 8; i += blockDim.x)
        Wl[i] = W4[(i >> 3) * 16 + half * 8 + (i & 7)];
    if (threadIdx.x < 8) Bl8[threadIdx.x] = B4[half * 8 + threadIdx.x];
    __syncthreads();
    int idx = bi * blockDim.x + threadIdx.x;
    if (idx >= n * 8) return;
    int row = idx >> 3;
    int c8 = idx & 7;
    const float* xr = X + (long)row * 128;
    float4 acc = Bl8[c8];
#pragma unroll 8
    for (int k = 0; k < 128; ++k) {
        float xv = xr[k];
        float4 w = Wl[k * 8 + c8];
        acc.x = fmaf(xv, w.x, acc.x);
        acc.y = fmaf(xv, w.y, acc.y);
        acc.z = fmaf(xv, w.z, acc.z);
        acc.w = fmaf(xv, w.w, acc.w);
    }
    S4out[(long)row * 16 + half * 8 + c8] = acc;
}

// ---------------- quarter-wave aggregation core ----------------
#define FMA4(A, V, W4)                                                        \
    A.x = fmaf(V.x, W4, A.x); A.y = fmaf(V.y, W4, A.y);                       \
    A.z = fmaf(V.z, W4, A.z); A.w = fmaf(V.w, W4, A.w);

#define AGG4_BODY(R4)                                                         \
    int beg = rowptr[wid], end = rowptr[wid + 1];                             \
    float4 a0 = make_float4(0.f, 0.f, 0.f, 0.f), a1 = a0, a2 = a0, a3 = a0;   \
    int j = beg;                                                              \
    for (; j + 16 <= end; j += 16) {                                          \
        long long p0 = ep[j + q], p1 = ep[j + 4 + q];                         \
        long long p2 = ep[j + 8 + q], p3 = ep[j + 12 + q];                    \
        float4 v0 = S4[(long)(int)(unsigned)p0 * R4 + sub];                   \
        float4 v1 = S4[(long)(int)(unsigned)p1 * R4 + sub];                   \
        float4 v2 = S4[(long)(int)(unsigned)p2 * R4 + sub];                   \
        float4 v3 = S4[(long)(int)(unsigned)p3 * R4 + sub];                   \
        float w0 = __int_as_float((int)(p0 >> 32));                           \
        float w1 = __int_as_float((int)(p1 >> 32));                           \
        float w2 = __int_as_float((int)(p2 >> 32));                           \
        float w3 = __int_as_float((int)(p3 >> 32));                           \
        FMA4(a0, v0, w0) FMA4(a1, v1, w1) FMA4(a2, v2, w2) FMA4(a3, v3, w3)   \
    }                                                                         \
    for (; j + 4 <= end; j += 4) {                                            \
        long long p0 = ep[j + q];                                             \
        float4 v0 = S4[(long)(int)(unsigned)p0 * R4 + sub];                   \
        float w0 = __int_as_float((int)(p0 >> 32));                           \
        FMA4(a0, v0, w0)                                                      \
    }                                                                         \
    if (j < end) {                                                            \
        int eidx = j + q;                                                     \
        long long p0 = ep[(eidx < end) ? eidx : (end - 1)];                   \
        float4 v0 = S4[(long)(int)(unsigned)p0 * R4 + sub];                   \
        float w0 = (eidx < end) ? __int_as_float((int)(p0 >> 32)) : 0.f;      \
        FMA4(a0, v0, w0)                                                      \
    }                                                                         \
    float4 acc;                                                               \
    acc.x = (a0.x + a1.x) + (a2.x + a3.x);                                    \
    acc.y = (a0.y + a1.y) + (a2.y + a3.y);                                    \
    acc.z = (a0.z + a1.z) + (a2.z + a3.z);                                    \
    acc.w = (a0.w + a1.w) + (a2.w + a3.w);                                    \
    acc.x += __shfl_xor(acc.x, 16); acc.y += __shfl_xor(acc.y, 16);           \
    acc.z += __shfl_xor(acc.z, 16); acc.w += __shfl_xor(acc.w, 16);           \
    acc.x += __shfl_xor(acc.x, 32); acc.y += __shfl_xor(acc.y, 32);           \
    acc.z += __shfl_xor(acc.z, 32); acc.w += __shfl_xor(acc.w, 32);

// in-wave lin tail via WAVE-PRIVATE LDS hrow (no block barrier needed:
// hrow[w] is written and read only by wave w; hardware lgkmcnt orders it).
// quarters split k (16 each), cross-quarter shuffle reduce, q==0 writes.
#define LIN_TAIL(C4OUT)                                                       \
    if (sub < C4OUT) {                                                        \
        float4 o = make_float4(0.f, 0.f, 0.f, 0.f);                           \
        const float* hr = hrow[w];                                            \
        _Pragma("unroll")                                                     \
        for (int kk = 0; kk < 16; ++kk) {                                     \
            float hv = hr[16 * q + kk];                                       \
            float4 wv = Wl[(16 * q + kk) * C4OUT + sub];                      \
            FMA4(o, wv, hv)                                                   \
        }                                                                     \
        o.x += __shfl_xor(o.x, 16); o.y += __shfl_xor(o.y, 16);               \
        o.z += __shfl_xor(o.z, 16); o.w += __shfl_xor(o.w, 16);               \
        o.x += __shfl_xor(o.x, 32); o.y += __shfl_xor(o.y, 32);               \
        o.z += __shfl_xor(o.z, 32); o.w += __shfl_xor(o.w, 32);               \
        if (q == 0) {                                                         \
            float4 b = Bl[sub];                                               \
            o.x += b.x; o.y += b.y; o.z += b.z; o.w += b.w;                   \
            S4out[(long)wid * C4OUT + sub] = o;                               \
        }                                                                     \
    }

// layer 0: h = relu(agg(S)); write H; S_next = h@W1+b1
__global__ void agg_relu_lin_kernel(const float4* __restrict__ S4,
                                    const int* __restrict__ rowptr,
                                    const long long* __restrict__ ep,
                                    const float4* __restrict__ W4,  // [64*16]
                                    const float4* __restrict__ B4,  // [16]
                                    float4* __restrict__ H4,
                                    float4* __restrict__ S4out, int n) {
    __shared__ float4 Wl[64 * 16];
    __shared__ float4 Bl[16];
    __shared__ float hrow[4][64];
    for (int i = threadIdx.x; i < 64 * 16; i += blockDim.x) Wl[i] = W4[i];
    if (threadIdx.x < 16) Bl[threadIdx.x] = B4[threadIdx.x];
    __syncthreads();   // only barrier: W-tile staging
    int wid = (blockIdx.x * blockDim.x + threadIdx.x) >> 6;
    int lane = threadIdx.x & 63;
    int q = lane >> 4, sub = lane & 15;
    int w = threadIdx.x >> 6;
    if (wid >= n) return;
    AGG4_BODY(16)
    if (q == 0) {
        float4 h = make_float4(fmaxf(acc.x, 0.f), fmaxf(acc.y, 0.f),
                               fmaxf(acc.z, 0.f), fmaxf(acc.w, 0.f));
        H4[(long)wid * 16 + sub] = h;
        ((float4*)hrow[w])[sub] = h;
    }
    LIN_TAIL(16)
}

// layers 1-2: h = gn(relu(agg)) + H (in-place); S_next = h@W+b
template <int C4OUT>
__global__ void agg_gn_lin_kernel(const float4* __restrict__ S4,
                                  const int* __restrict__ rowptr,
                                  const long long* __restrict__ ep,
                                  const float4* __restrict__ gamma,
                                  const float4* __restrict__ beta,
                                  const float4* __restrict__ W4,  // [64*C4OUT]
                                  const float4* __restrict__ B4,  // [C4OUT]
                                  float4* __restrict__ H4,
                                  float4* __restrict__ S4out, int n) {
    __shared__ float4 Wl[64 * C4OUT];
    __shared__ float4 Bl[C4OUT];
    __shared__ float hrow[4][64];
    for (int i = threadIdx.x; i < 64 * C4OUT; i += blockDim.x) Wl[i] = W4[i];
    if (threadIdx.x < C4OUT) Bl[threadIdx.x] = B4[threadIdx.x];
    __syncthreads();   // only barrier: W-tile staging
    int wid = (blockIdx.x * blockDim.x + threadIdx.x) >> 6;
    int lane = threadIdx.x & 63;
    int q = lane >> 4, sub = lane & 15;
    int w = threadIdx.x >> 6;
    if (wid >= n) return;
    AGG4_BODY(16)
    if (q == 0) {
        float p0 = fmaxf(acc.x, 0.f), p1 = fmaxf(acc.y, 0.f);
        float p2 = fmaxf(acc.z, 0.f), p3 = fmaxf(acc.w, 0.f);
        float dA = 0.5f * (p0 - p1);
        float dB = 0.5f * (p2 - p3);
        float rsA = rsqrtf(dA * dA + EPS);
        float rsB = rsqrtf(dB * dB + EPS);
        float4 g = gamma[sub], be = beta[sub];
        long off = (long)wid * 16 + sub;
        float4 h = H4[off];
        h.x += dA * rsA * g.x + be.x;
        h.y += -dA * rsA * g.y + be.y;
        h.z += dB * rsB * g.z + be.z;
        h.w += -dB * rsB * g.w + be.w;
        H4[off] = h;
        ((float4*)hrow[w])[sub] = h;
    }
    LIN_TAIL(C4OUT)
}

// layer 3: log_softmax over 40 classes (10 float4 per row; sub<10 valid)
__global__ void agg_lsm_kernel(const float4* __restrict__ S4,
                               const int* __restrict__ rowptr,
                               const long long* __restrict__ ep,
                               float4* __restrict__ out4, int n) {
    int wid = (blockIdx.x * blockDim.x + threadIdx.x) >> 6;
    int lane = threadIdx.x & 63;
    int q = lane >> 4;
    int sub0 = lane & 15;
    int sub = (sub0 < 10) ? sub0 : 9;  // clamp: in-bounds dup loads, ignored
    if (wid >= n) return;
    AGG4_BODY(10)
    bool valid = sub0 < 10;
    float m = valid ? fmaxf(fmaxf(acc.x, acc.y), fmaxf(acc.z, acc.w)) : -INFINITY;
#pragma unroll
    for (int mk = 8; mk; mk >>= 1) m = fmaxf(m, __shfl_xor(m, mk));
    float ex = valid ? (expf(acc.x - m) + expf(acc.y - m) +
                        expf(acc.z - m) + expf(acc.w - m)) : 0.f;
#pragma unroll
    for (int mk = 8; mk; mk >>= 1) ex += __shfl_xor(ex, mk);
    float l = m + logf(ex);
    if (q == 0 && valid)
        out4[(long)wid * 10 + sub0] =
            make_float4(acc.x - l, acc.y - l, acc.z - l, acc.w - l);
}

extern "C" void kernel_launch(void* const* d_in, const int* in_sizes, int n_in,
                              void* d_out, int out_size, void* d_ws,
                              size_t ws_size, hipStream_t stream) {
    const float* x = (const float*)d_in[0];
    const int* src = (const int*)d_in[1];
    const int* tgt = (const int*)d_in[2];
    const float* mv = (const float*)d_in[3];
    const float* W0 = (const float*)d_in[4];
    const float* b0 = (const float*)d_in[5];
    const float* W1 = (const float*)d_in[6];
    const float* b1 = (const float*)d_in[7];
    const float* W2 = (const float*)d_in[8];
    const float* b2 = (const float*)d_in[9];
    const float* W3 = (const float*)d_in[10];
    const float* b3 = (const float*)d_in[11];
    const float* g1 = (const float*)d_in[12];
    const float* beta1 = (const float*)d_in[13];
    const float* g2 = (const float*)d_in[14];
    const float* beta2 = (const float*)d_in[15];

    const int N = in_sizes[0] / 128;
    const int E = in_sizes[1];

    float* buf_s0 = (float*)d_ws;               // [N,64] S ping
    float* buf_s1 = buf_s0 + (size_t)N * 64;    // [N,64] S pong
    float* buf_h = buf_s1 + (size_t)N * 64;     // [N,64] h / residual
    int* rowptr = (int*)(buf_h + (size_t)N * 64);  // [N+1]
    int* cursor = rowptr + (N + 1);             // [N]
    int* cnt = cursor + N;                      // [N]
    int* bsum = cnt + N;                        // [<=1024]
    long long* epack = (long long*)(((uintptr_t)(bsum + 1024) + 15) & ~(uintptr_t)15);

    const int BLK = 256;
    auto grid = [](long total, int blk) { return (int)((total + blk - 1) / blk); };
    const int scanBlocks = grid(N, SCAN_BLK);
    const int fillBlocks = grid(E, BLK);
    const int halfBlocks = grid((long)N * 8, BLK);

    // ---- CSR build ----
    hipMemsetAsync(cnt, 0, (size_t)N * sizeof(int), stream);
    count_kernel<<<grid(E, BLK), BLK, 0, stream>>>(tgt, cnt, E);
    scan_p1<<<scanBlocks, SCAN_BLK, 0, stream>>>(cnt, bsum, N);
    scan_p23<<<scanBlocks, SCAN_BLK, 0, stream>>>(cnt, bsum, rowptr, cursor, N);

    // ---- fused: CSR fill + layer-0 linear (half-tile LDS) -> S0 ----
    fill_lin0_kernel<<<fillBlocks + 2 * halfBlocks, BLK, 0, stream>>>(
        src, tgt, mv, cursor, epack, E, x, (const float4*)W0, (const float4*)b0,
        (float4*)buf_s0, N, fillBlocks, halfBlocks);

    const int aggBlocks = grid((long)N * 64, BLK);  // 4 waves (nodes) per block

    // ---- layer 0 agg + lin1: gathers S0 -> H, S1 ----
    agg_relu_lin_kernel<<<aggBlocks, BLK, 0, stream>>>(
        (const float4*)buf_s0, rowptr, epack, (const float4*)W1,
        (const float4*)b1, (float4*)buf_h, (float4*)buf_s1, N);

    // ---- layer 1 agg + lin2: gathers S1 -> H (in-place), S0 ----
    agg_gn_lin_kernel<16><<<aggBlocks, BLK, 0, stream>>>(
        (const float4*)buf_s1, rowptr, epack, (const float4*)g1,
        (const float4*)beta1, (const float4*)W2, (const float4*)b2,
        (float4*)buf_h, (float4*)buf_s0, N);

    // ---- layer 2 agg + lin3: gathers S0 -> H (in-place), S1 as [N,40] ----
    agg_gn_lin_kernel<10><<<aggBlocks, BLK, 0, stream>>>(
        (const float4*)buf_s0, rowptr, epack, (const float4*)g2,
        (const float4*)beta2, (const float4*)W3, (const float4*)b3,
        (float4*)buf_h, (float4*)buf_s1, N);

    // ---- layer 3: out = log_softmax(agg(S1)) ----
    agg_lsm_kernel<<<aggBlocks, BLK, 0, stream>>>(
        (const float4*)buf_s1, rowptr, epack, (float4*)d_out, N);
}